// Round 17
// baseline (56.271 us; speedup 1.0000x reference)
//
#include <hip/hip_runtime.h>
#include <hip/hip_bf16.h>
#include <hip/hip_fp16.h>

#define BB 16
#define TT 2048
#define DD 384
#define GG 2048          // total chains = BB * 128
#define CC 256           // chunks over T
#define LL 8             // steps per chunk (CC*LL == TT)
#define HSTRIDE (DD + 8) // 392 ≡ 8 (mod 32): conflict-free LDS access
#define EPSF 1e-8f
#define RCPF(x) __builtin_amdgcn_rcpf(x)

// Wc float4 layout (first 30 KB of d_ws):
//   idx (m*4+k)*128 + n      -> (W[m][k][3n], W[m][k][3n+1], W[m][k][3n+2], 0)
//   idx 1536 + m*128 + n     -> (bias[m][3n], bias[m][3n+1], bias[m][3n+2], 0)

// ---------- kernel 0: combined weights, packed float4 output (1024-thr, 64-way d-split) ----------
__global__ __launch_bounds__(1024) void precompute_wc(
        const float* __restrict__ W_in,
        const float* __restrict__ W_biv,
        const float* __restrict__ W_dec,
        const float* __restrict__ W_inj,
        const float* __restrict__ b_biv,
        const float* __restrict__ b_dec,
        const float* __restrict__ b_inj,
        float* __restrict__ Wc) {
    int m = blockIdx.x;
    int jl = threadIdx.x & 15;
    int dp = threadIdx.x >> 4;           // 0..63
    int j = blockIdx.y * 16 + jl;        // 0..383
    const float* __restrict__ W = (m == 0) ? W_biv : (m == 1) ? W_dec : W_inj;
    float a[4] = {0.f, 0.f, 0.f, 0.f};
#pragma unroll
    for (int d = dp; d < DD; d += 64) {
        float wv = W[d * DD + j];
#pragma unroll
        for (int k = 0; k < 4; ++k) a[k] = fmaf(W_in[k * DD + d], wv, a[k]);
    }
    __shared__ float red[64][17][4];
#pragma unroll
    for (int k = 0; k < 4; ++k) red[dp][jl][k] = a[k];
    __syncthreads();
    for (int s = 32; s >= 1; s >>= 1) {
        if (dp < s) {
#pragma unroll
            for (int k = 0; k < 4; ++k) red[dp][jl][k] += red[dp + s][jl][k];
        }
        __syncthreads();
    }
    int n = j / 3, comp = j - 3 * n;
    if (dp < 4) {
        Wc[((m * 4 + dp) * 128 + n) * 4 + comp] = red[0][jl][dp];
    } else if (dp == 4) {
#pragma unroll
        for (int k = 0; k < 4; ++k) Wc[((m * 4 + k) * 128 + n) * 4 + 3] = 0.f;
        Wc[(1536 + m * 128 + n) * 4 + 3] = 0.f;
    } else if (dp == 5) {
        const float* bsrc = (m == 0) ? b_biv : (m == 1) ? b_dec : b_inj;
        Wc[(1536 + m * 128 + n) * 4 + comp] = bsrc[j];
    }
}

// ---------- per-chain weights & per-step math ----------
struct Wts {
    float wb[4][3], wd[4][3], wi[4][3];
    float bb[3], bd[3], bj[3];
};

__device__ __forceinline__ void load_wts(const float4* __restrict__ Wc4, int n, Wts& W) {
#pragma unroll
    for (int k = 0; k < 4; ++k) {
        float4 v = Wc4[(0 * 4 + k) * 128 + n];
        W.wb[k][0] = v.x; W.wb[k][1] = v.y; W.wb[k][2] = v.z;
    }
#pragma unroll
    for (int k = 0; k < 4; ++k) {
        float4 v = Wc4[(1 * 4 + k) * 128 + n];
        W.wd[k][0] = v.x; W.wd[k][1] = v.y; W.wd[k][2] = v.z;
    }
#pragma unroll
    for (int k = 0; k < 4; ++k) {
        float4 v = Wc4[(2 * 4 + k) * 128 + n];
        W.wi[k][0] = v.x; W.wi[k][1] = v.y; W.wi[k][2] = v.z;
    }
    float4 b0 = Wc4[1536 + 0 * 128 + n];
    float4 b1 = Wc4[1536 + 1 * 128 + n];
    float4 b2 = Wc4[1536 + 2 * 128 + n];
    W.bb[0] = b0.x; W.bb[1] = b0.y; W.bb[2] = b0.z;
    W.bd[0] = b1.x; W.bd[1] = b1.y; W.bd[2] = b1.z;
    W.bj[0] = b2.x; W.bj[1] = b2.y; W.bj[2] = b2.z;
}

#define DOTW(M, c, bias) \
    fmaf(q.w, W.M[3][c], fmaf(q.z, W.M[2][c], fmaf(q.y, W.M[1][c], fmaf(q.x, W.M[0][c], bias))))

// w = cos(nb/2) ~ 1 - u/8 + u^2/384 ; s = sin(nb/2)/nb ~ 1/2 - u/48 + u^2/3840 ; u = nb^2.
__device__ __forceinline__ void step_parts(const Wts& W, float4 q,
        float& dec0, float& dec1, float& dec2,
        float& w, float& qx, float& qy, float& qz,
        float& i0, float& i1, float& i2) {
    float bx = DOTW(wb, 0, W.bb[0]);
    float by = DOTW(wb, 1, W.bb[1]);
    float bz = DOTW(wb, 2, W.bb[2]);
    float d0 = DOTW(wd, 0, W.bd[0]);
    float d1 = DOTW(wd, 1, W.bd[1]);
    float d2 = DOTW(wd, 2, W.bd[2]);
    i0 = DOTW(wi, 0, W.bj[0]);
    i1 = DOTW(wi, 1, W.bj[1]);
    i2 = DOTW(wi, 2, W.bj[2]);
    dec0 = RCPF(1.f + __expf(-d0));
    dec1 = RCPF(1.f + __expf(-d1));
    dec2 = RCPF(1.f + __expf(-d2));
    float u = fmaf(bx, bx, fmaf(by, by, bz * bz));
    w = fmaf(u, fmaf(u, 2.6041667e-3f, -0.125f), 1.f);
    float s = fmaf(u, fmaf(u, 2.6041667e-4f, -2.0833333e-2f), 0.5f);
    qx = s * bz; qy = -s * by; qz = s * bx;
}

// build the step's 3x3 matrix (rows scaled by dec) + injection
__device__ __forceinline__ void step_matrix(const Wts& W, float4 q,
                                            float M[9], float& i0, float& i1, float& i2) {
    float dec0, dec1, dec2, w, qx, qy, qz;
    step_parts(W, q, dec0, dec1, dec2, w, qx, qy, qz, i0, i1, i2);
    float xx = qx*qx, yy = qy*qy, zz = qz*qz;
    float xy = qx*qy, xz = qx*qz, yz = qy*qz;
    float wxs = w*qx, wys = w*qy, wzs = w*qz;
    M[0] = dec0 * (1.f - 2.f*(yy+zz));
    M[1] = dec0 * (2.f*(xy - wzs));
    M[2] = dec0 * (2.f*(xz + wys));
    M[3] = dec1 * (2.f*(xy + wzs));
    M[4] = dec1 * (1.f - 2.f*(xx+zz));
    M[5] = dec1 * (2.f*(yz - wxs));
    M[6] = dec2 * (2.f*(xz - wys));
    M[7] = dec2 * (2.f*(yz + wxs));
    M[8] = dec2 * (1.f - 2.f*(xx+yy));
}

// A (12-vec affine) <- step0 map directly (peeled identity multiply)
__device__ __forceinline__ void step_init12(const Wts& W, float4 q, float A[12]) {
    float M[9], i0, i1, i2;
    step_matrix(W, q, M, i0, i1, i2);
#pragma unroll
    for (int e = 0; e < 9; ++e) A[e] = M[e];
    A[9] = i0; A[10] = i1; A[11] = i2;
}

// A <- step_map ∘ A
__device__ __forceinline__ void step_compose12(const Wts& W, float4 q, float A[12]) {
    float M[9], i0, i1, i2;
    step_matrix(W, q, M, i0, i1, i2);
    float n0 = fmaf(M[0], A[0], fmaf(M[1], A[3], M[2] * A[6]));
    float n1 = fmaf(M[0], A[1], fmaf(M[1], A[4], M[2] * A[7]));
    float n2 = fmaf(M[0], A[2], fmaf(M[1], A[5], M[2] * A[8]));
    float n3 = fmaf(M[3], A[0], fmaf(M[4], A[3], M[5] * A[6]));
    float n4 = fmaf(M[3], A[1], fmaf(M[4], A[4], M[5] * A[7]));
    float n5 = fmaf(M[3], A[2], fmaf(M[4], A[5], M[5] * A[8]));
    float n6 = fmaf(M[6], A[0], fmaf(M[7], A[3], M[8] * A[6]));
    float n7 = fmaf(M[6], A[1], fmaf(M[7], A[4], M[8] * A[7]));
    float n8 = fmaf(M[6], A[2], fmaf(M[7], A[5], M[8] * A[8]));
    float n9  = fmaf(M[0], A[9], fmaf(M[1], A[10], fmaf(M[2], A[11], i0)));
    float n10 = fmaf(M[3], A[9], fmaf(M[4], A[10], fmaf(M[5], A[11], i1)));
    float n11 = fmaf(M[6], A[9], fmaf(M[7], A[10], fmaf(M[8], A[11], i2)));
    A[0]=n0; A[1]=n1; A[2]=n2; A[3]=n3; A[4]=n4; A[5]=n5;
    A[6]=n6; A[7]=n7; A[8]=n8; A[9]=n9; A[10]=n10; A[11]=n11;
}

__device__ __forceinline__ void step_apply(const Wts& W, float4 q,
                                           float& vx, float& vy, float& vz) {
    float dec0, dec1, dec2, w, qx, qy, qz, i0, i1, i2;
    step_parts(W, q, dec0, dec1, dec2, w, qx, qy, qz, i0, i1, i2);
    float tx = 2.f * (qy * vz - qz * vy);
    float ty = 2.f * (qz * vx - qx * vz);
    float tz = 2.f * (qx * vy - qy * vx);
    float rx = vx + w * tx + (qy * tz - qz * ty);
    float ry = vy + w * ty + (qz * tx - qx * tz);
    float rz = vz + w * tz + (qx * ty - qy * tx);
    vx = fmaf(dec0, rx, i0);
    vy = fmaf(dec1, ry, i1);
    vz = fmaf(dec2, rz, i2);
}

// R = C ∘ P   (12-vec affine maps)
#define COMPOSE(R, C, P)                                                    \
    R[0] = fmaf(C[0], P[0], fmaf(C[1], P[3], C[2] * P[6]));                 \
    R[1] = fmaf(C[0], P[1], fmaf(C[1], P[4], C[2] * P[7]));                 \
    R[2] = fmaf(C[0], P[2], fmaf(C[1], P[5], C[2] * P[8]));                 \
    R[3] = fmaf(C[3], P[0], fmaf(C[4], P[3], C[5] * P[6]));                 \
    R[4] = fmaf(C[3], P[1], fmaf(C[4], P[4], C[5] * P[7]));                 \
    R[5] = fmaf(C[3], P[2], fmaf(C[4], P[5], C[5] * P[8]));                 \
    R[6] = fmaf(C[6], P[0], fmaf(C[7], P[3], C[8] * P[6]));                 \
    R[7] = fmaf(C[6], P[1], fmaf(C[7], P[4], C[8] * P[7]));                 \
    R[8] = fmaf(C[6], P[2], fmaf(C[7], P[5], C[8] * P[8]));                 \
    R[9]  = fmaf(C[0], P[9], fmaf(C[1], P[10], fmaf(C[2], P[11], C[9])));   \
    R[10] = fmaf(C[3], P[9], fmaf(C[4], P[10], fmaf(C[5], P[11], C[10])));  \
    R[11] = fmaf(C[6], P[9], fmaf(C[7], P[10], fmaf(C[8], P[11], C[11])));

__device__ __forceinline__ void pack12(const float A[12], float4* dst) {
    union { __half2 h2[8]; float4 f4[2]; } u;
#pragma unroll
    for (int e = 0; e < 6; ++e) u.h2[e] = __floats2half2_rn(A[2 * e], A[2 * e + 1]);
    u.h2[6] = __floats2half2_rn(0.f, 0.f);
    u.h2[7] = __floats2half2_rn(0.f, 0.f);
    dst[0] = u.f4[0];
    dst[1] = u.f4[1];
}

__device__ __forceinline__ void unpack12(const float4* src, float A[12]) {
    union { __half2 h2[8]; float4 f4[2]; } u;
    u.f4[0] = src[0]; u.f4[1] = src[1];
#pragma unroll
    for (int e = 0; e < 6; ++e) {
        float2 v = __half22float2(u.h2[e]);
        A[2 * e] = v.x; A[2 * e + 1] = v.y;
    }
}

// packed fp16 3-vector (8 B)
__device__ __forceinline__ uint2 packh3(float a, float b, float c) {
    __half2 lo = __floats2half2_rn(a, b);
    __half2 hi = __floats2half2_rn(c, 0.f);
    uint2 r;
    r.x = *(unsigned int*)&lo;
    r.y = *(unsigned int*)&hi;
    return r;
}

__device__ __forceinline__ void unpackh3(uint2 v, float& a, float& b, float& c) {
    __half2 lo = *(__half2*)&v.x;
    __half2 hi = *(__half2*)&v.y;
    float2 l2 = __half22float2(lo);
    float2 h2v = __half22float2(hi);
    a = l2.x; b = l2.y; c = h2v.x;
}

// ---------- kernel A: composed affine map; snapshots prefix-2, prefix-4, steps-4..5 ----------
// All map buffers: [CC][GG] x 2 float4 (12 halves packed, 4 pad)
__global__ __launch_bounds__(128) void chunk_compose(
        const float* __restrict__ quat,
        const float4* __restrict__ Wc4,
        float4* __restrict__ AffH,
        float4* __restrict__ P2,    // steps 0-1 composite  (prefix-2 map)
        float4* __restrict__ P4,    // steps 0-3 composite  (prefix-4 map)
        float4* __restrict__ C45) { // steps 4-5 composite
    int c = blockIdx.x, b = blockIdx.y, n = threadIdx.x;
    int g = b * 128 + n;
    size_t idx = ((size_t)c * GG + g) * 2;

    const float4* __restrict__ qp = (const float4*)(quat + (size_t)b * TT * 4) + c * LL;
    float4 q[LL];
#pragma unroll
    for (int t = 0; t < LL; ++t) q[t] = qp[t];

    Wts W;
    load_wts(Wc4, n, W);

    // two independent half-chunk chains, with mid-chain snapshots
    float Alo[12], Ahi[12];
    step_init12(W, q[0], Alo);
    step_init12(W, q[4], Ahi);
    step_compose12(W, q[1], Alo);
    step_compose12(W, q[5], Ahi);
    pack12(Alo, P2 + idx);          // fire-and-forget snapshot
    pack12(Ahi, C45 + idx);
    step_compose12(W, q[2], Alo);
    step_compose12(W, q[6], Ahi);
    step_compose12(W, q[3], Alo);
    step_compose12(W, q[7], Ahi);
    pack12(Alo, P4 + idx);
    float A[12];
    COMPOSE(A, Ahi, Alo);
    pack12(A, AffH + idx);
}

// ---------- kernel B: wave-parallel scan, 4 chunks per lane ----------
// Hs layout: [CC][GG] uint2 (fp16-packed chunk start state)
__global__ __launch_bounds__(256) void chunk_scan(
        const float4* __restrict__ AffH,
        uint2* __restrict__ Hs) {
    int g = (blockIdx.x * 256 + threadIdx.x) >> 6;   // chain (wave-uniform)
    int l = threadIdx.x & 63;                        // lane = quad index

    float m[4][12];
#pragma unroll
    for (int k = 0; k < 4; ++k)
        unpack12(AffH + ((size_t)(4 * l + k) * GG + g) * 2, m[k]);

    float q01[12], q012[12], Q[12];
    COMPOSE(q01, m[1], m[0]);
    COMPOSE(q012, m[2], q01);
    COMPOSE(Q, m[3], q012);

    float P[12];
#pragma unroll
    for (int k = 0; k < 12; ++k) P[k] = __shfl_up(Q[k], 1);
    if (l == 0) {
        P[0]=1.f; P[1]=0.f; P[2]=0.f; P[3]=0.f; P[4]=1.f; P[5]=0.f;
        P[6]=0.f; P[7]=0.f; P[8]=1.f; P[9]=0.f; P[10]=0.f; P[11]=0.f;
    }
#pragma unroll
    for (int sft = 1; sft < 64; sft <<= 1) {
        float S[12], N[12];
#pragma unroll
        for (int k = 0; k < 12; ++k) S[k] = __shfl_up(P[k], sft);
        COMPOSE(N, P, S);
        bool act = (l >= sft);
#pragma unroll
        for (int k = 0; k < 12; ++k) P[k] = act ? N[k] : P[k];
    }

    float h0 = P[9], h1 = P[10], h2 = P[11];
#pragma unroll
    for (int k = 0; k < 4; ++k) {
        Hs[(size_t)(4 * l + k) * GG + g] = packh3(h0, h1, h2);
        if (k < 3) {
            float n0 = fmaf(m[k][0], h0, fmaf(m[k][1], h1, fmaf(m[k][2], h2, m[k][9])));
            float n1 = fmaf(m[k][3], h0, fmaf(m[k][4], h1, fmaf(m[k][5], h2, m[k][10])));
            float n2 = fmaf(m[k][6], h0, fmaf(m[k][7], h1, fmaf(m[k][8], h2, m[k][11])));
            h0 = n0; h1 = n1; h2 = n2;
        }
    }
}

// ---------- kernel C: replay as FOUR independent 2-step chains + projection ----------
__global__ __launch_bounds__(128) void chunk_apply_out(
        const float* __restrict__ quat,
        const float4* __restrict__ Wc4,
        const float* __restrict__ W_out,   // [DD][4]
        const uint2* __restrict__ Hs,      // [CC][GG] fp16-packed
        const float4* __restrict__ P2,
        const float4* __restrict__ P4,
        const float4* __restrict__ C45,
        float* __restrict__ out) {         // [BB][TT][4]
    int c = blockIdx.x, b = blockIdx.y, n = threadIdx.x;
    int g = b * 128 + n;
    size_t idx = ((size_t)c * GG + g) * 2;

    const float4* __restrict__ qp = (const float4*)(quat + (size_t)b * TT * 4) + c * LL;
    float4 q[LL];
#pragma unroll
    for (int t = 0; t < LL; ++t) q[t] = qp[t];

    float ax, ay, az;
    unpackh3(Hs[(size_t)c * GG + g], ax, ay, az);

    Wts W;
    load_wts(Wc4, n, W);

    __shared__ float H[LL][HSTRIDE];
    int j0 = 3 * n;

    // seed 4 chains: A at step0, B at step2 (P2·hA), C at step4 (P4·hA), D at step6 (C45·hC)
    float m2[12], m4[12], m45[12];
    unpack12(P2 + idx, m2);
    unpack12(P4 + idx, m4);
    unpack12(C45 + idx, m45);
    float bx = fmaf(m2[0], ax, fmaf(m2[1], ay, fmaf(m2[2], az, m2[9])));
    float by = fmaf(m2[3], ax, fmaf(m2[4], ay, fmaf(m2[5], az, m2[10])));
    float bz = fmaf(m2[6], ax, fmaf(m2[7], ay, fmaf(m2[8], az, m2[11])));
    float cx = fmaf(m4[0], ax, fmaf(m4[1], ay, fmaf(m4[2], az, m4[9])));
    float cy = fmaf(m4[3], ax, fmaf(m4[4], ay, fmaf(m4[5], az, m4[10])));
    float cz = fmaf(m4[6], ax, fmaf(m4[7], ay, fmaf(m4[8], az, m4[11])));
    float dx = fmaf(m45[0], cx, fmaf(m45[1], cy, fmaf(m45[2], cz, m45[9])));
    float dy = fmaf(m45[3], cx, fmaf(m45[4], cy, fmaf(m45[5], cz, m45[10])));
    float dz = fmaf(m45[6], cx, fmaf(m45[7], cy, fmaf(m45[8], cz, m45[11])));

#pragma unroll
    for (int t = 0; t < 2; ++t) {
        step_apply(W, q[t], ax, ay, az);
        step_apply(W, q[2 + t], bx, by, bz);
        step_apply(W, q[4 + t], cx, cy, cz);
        step_apply(W, q[6 + t], dx, dy, dz);
        H[t][j0] = ax;     H[t][j0 + 1] = ay;     H[t][j0 + 2] = az;
        H[2 + t][j0] = bx; H[2 + t][j0 + 1] = by; H[2 + t][j0 + 2] = bz;
        H[4 + t][j0] = cx; H[4 + t][j0 + 1] = cy; H[4 + t][j0 + 2] = cz;
        H[6 + t][j0] = dx; H[6 + t][j0 + 1] = dy; H[6 + t][j0 + 2] = dz;
    }
    __syncthreads();

    // projection: thread -> (row r = n>>4, part p = n&15); d = p + 16j
    int r = n >> 4, p = n & 15;
    float s0 = 0.f, s1 = 0.f, s2 = 0.f, s3 = 0.f;
#pragma unroll 8
    for (int j = 0; j < DD / 16; ++j) {
        int d = p + 16 * j;
        float hv = H[r][d];
        float4 wv = *(const float4*)(W_out + (size_t)d * 4);
        s0 = fmaf(hv, wv.x, s0);
        s1 = fmaf(hv, wv.y, s1);
        s2 = fmaf(hv, wv.z, s2);
        s3 = fmaf(hv, wv.w, s3);
    }
#pragma unroll
    for (int off = 1; off <= 8; off <<= 1) {
        s0 += __shfl_xor(s0, off);
        s1 += __shfl_xor(s1, off);
        s2 += __shfl_xor(s2, off);
        s3 += __shfl_xor(s3, off);
    }
    if (p == 0) {
        float norm = fmaxf(sqrtf(fmaf(s0, s0, fmaf(s1, s1, fmaf(s2, s2, s3 * s3)))), EPSF);
        float inv = RCPF(norm);
        float* outp = out + ((size_t)b * TT + (size_t)c * LL + r) * 4;
        *(float4*)outp = make_float4(s0 * inv, s1 * inv, s2 * inv, s3 * inv);
    }
}

extern "C" void kernel_launch(void* const* d_in, const int* in_sizes, int n_in,
                              void* d_out, int out_size, void* d_ws, size_t ws_size,
                              hipStream_t stream) {
    const float* quat  = (const float*)d_in[0];
    const float* W_in  = (const float*)d_in[1];
    const float* W_biv = (const float*)d_in[2];
    const float* b_biv = (const float*)d_in[3];
    const float* W_dec = (const float*)d_in[4];
    const float* b_dec = (const float*)d_in[5];
    const float* W_inj = (const float*)d_in[6];
    const float* b_inj = (const float*)d_in[7];
    const float* W_out = (const float*)d_in[8];
    float* out = (float*)d_out;

    const size_t MAPB = (size_t)CC * GG * 32;      // 16.8 MB per fp16 map buffer
    const size_t AFF_OFF = 32768;
    const size_t P2_OFF  = AFF_OFF + MAPB;
    const size_t P4_OFF  = P2_OFF + MAPB;
    const size_t C45_OFF = P4_OFF + MAPB;
    const size_t HS_OFF  = C45_OFF + MAPB;

    float*  Wc   = (float*)d_ws;
    float4* Wc4  = (float4*)d_ws;
    float4* AffH = (float4*)((char*)d_ws + AFF_OFF);
    float4* P2   = (float4*)((char*)d_ws + P2_OFF);
    float4* P4   = (float4*)((char*)d_ws + P4_OFF);
    float4* C45  = (float4*)((char*)d_ws + C45_OFF);
    uint2*  Hs   = (uint2*)((char*)d_ws + HS_OFF);

    precompute_wc<<<dim3(3, DD / 16), dim3(1024), 0, stream>>>(
        W_in, W_biv, W_dec, W_inj, b_biv, b_dec, b_inj, Wc);
    chunk_compose<<<dim3(CC, BB), dim3(128), 0, stream>>>(quat, Wc4, AffH, P2, P4, C45);
    chunk_scan<<<dim3(GG / 4), dim3(256), 0, stream>>>(AffH, Hs);
    chunk_apply_out<<<dim3(CC, BB), dim3(128), 0, stream>>>(quat, Wc4, W_out, Hs,
                                                            P2, P4, C45, out);
}

// Round 18
// 52.389 us; speedup vs baseline: 1.0741x; 1.0741x over previous
//
#include <hip/hip_runtime.h>
#include <hip/hip_bf16.h>
#include <hip/hip_fp16.h>

#define BB 16
#define TT 2048
#define DD 384
#define GG 2048          // total chains = BB * 128
#define CC 256           // chunks over T
#define LL 8             // steps per chunk (CC*LL == TT)
#define HSTRIDE (DD + 8) // 392 ≡ 8 (mod 32): conflict-free LDS access
#define EPSF 1e-8f
#define RCPF(x) __builtin_amdgcn_rcpf(x)

// Wc float4 layout (first 30 KB of d_ws):
//   idx (m*4+k)*128 + n      -> (W[m][k][3n], W[m][k][3n+1], W[m][k][3n+2], 0)
//   idx 1536 + m*128 + n     -> (bias[m][3n], bias[m][3n+1], bias[m][3n+2], 0)

// ---------- kernel 0: combined weights, packed float4 output (1024-thr, 64-way d-split) ----------
__global__ __launch_bounds__(1024) void precompute_wc(
        const float* __restrict__ W_in,
        const float* __restrict__ W_biv,
        const float* __restrict__ W_dec,
        const float* __restrict__ W_inj,
        const float* __restrict__ b_biv,
        const float* __restrict__ b_dec,
        const float* __restrict__ b_inj,
        float* __restrict__ Wc) {
    int m = blockIdx.x;
    int jl = threadIdx.x & 15;
    int dp = threadIdx.x >> 4;           // 0..63
    int j = blockIdx.y * 16 + jl;        // 0..383
    const float* __restrict__ W = (m == 0) ? W_biv : (m == 1) ? W_dec : W_inj;
    float a[4] = {0.f, 0.f, 0.f, 0.f};
#pragma unroll
    for (int d = dp; d < DD; d += 64) {
        float wv = W[d * DD + j];
#pragma unroll
        for (int k = 0; k < 4; ++k) a[k] = fmaf(W_in[k * DD + d], wv, a[k]);
    }
    __shared__ float red[64][17][4];
#pragma unroll
    for (int k = 0; k < 4; ++k) red[dp][jl][k] = a[k];
    __syncthreads();
    for (int s = 32; s >= 1; s >>= 1) {
        if (dp < s) {
#pragma unroll
            for (int k = 0; k < 4; ++k) red[dp][jl][k] += red[dp + s][jl][k];
        }
        __syncthreads();
    }
    int n = j / 3, comp = j - 3 * n;
    if (dp < 4) {
        Wc[((m * 4 + dp) * 128 + n) * 4 + comp] = red[0][jl][dp];
    } else if (dp == 4) {
#pragma unroll
        for (int k = 0; k < 4; ++k) Wc[((m * 4 + k) * 128 + n) * 4 + 3] = 0.f;
        Wc[(1536 + m * 128 + n) * 4 + 3] = 0.f;
    } else if (dp == 5) {
        const float* bsrc = (m == 0) ? b_biv : (m == 1) ? b_dec : b_inj;
        Wc[(1536 + m * 128 + n) * 4 + comp] = bsrc[j];
    }
}

// ---------- per-chain weights & per-step math ----------
struct Wts {
    float wb[4][3], wd[4][3], wi[4][3];
    float bb[3], bd[3], bj[3];
};

__device__ __forceinline__ void load_wts(const float4* __restrict__ Wc4, int n, Wts& W) {
#pragma unroll
    for (int k = 0; k < 4; ++k) {
        float4 v = Wc4[(0 * 4 + k) * 128 + n];
        W.wb[k][0] = v.x; W.wb[k][1] = v.y; W.wb[k][2] = v.z;
    }
#pragma unroll
    for (int k = 0; k < 4; ++k) {
        float4 v = Wc4[(1 * 4 + k) * 128 + n];
        W.wd[k][0] = v.x; W.wd[k][1] = v.y; W.wd[k][2] = v.z;
    }
#pragma unroll
    for (int k = 0; k < 4; ++k) {
        float4 v = Wc4[(2 * 4 + k) * 128 + n];
        W.wi[k][0] = v.x; W.wi[k][1] = v.y; W.wi[k][2] = v.z;
    }
    float4 b0 = Wc4[1536 + 0 * 128 + n];
    float4 b1 = Wc4[1536 + 1 * 128 + n];
    float4 b2 = Wc4[1536 + 2 * 128 + n];
    W.bb[0] = b0.x; W.bb[1] = b0.y; W.bb[2] = b0.z;
    W.bd[0] = b1.x; W.bd[1] = b1.y; W.bd[2] = b1.z;
    W.bj[0] = b2.x; W.bj[1] = b2.y; W.bj[2] = b2.z;
}

#define DOTW(M, c, bias) \
    fmaf(q.w, W.M[3][c], fmaf(q.z, W.M[2][c], fmaf(q.y, W.M[1][c], fmaf(q.x, W.M[0][c], bias))))

// w = cos(nb/2) ~ 1 - u/8 + u^2/384 ; s = sin(nb/2)/nb ~ 1/2 - u/48 + u^2/3840 ; u = nb^2.
__device__ __forceinline__ void step_parts(const Wts& W, float4 q,
        float& dec0, float& dec1, float& dec2,
        float& w, float& qx, float& qy, float& qz,
        float& i0, float& i1, float& i2) {
    float bx = DOTW(wb, 0, W.bb[0]);
    float by = DOTW(wb, 1, W.bb[1]);
    float bz = DOTW(wb, 2, W.bb[2]);
    float d0 = DOTW(wd, 0, W.bd[0]);
    float d1 = DOTW(wd, 1, W.bd[1]);
    float d2 = DOTW(wd, 2, W.bd[2]);
    i0 = DOTW(wi, 0, W.bj[0]);
    i1 = DOTW(wi, 1, W.bj[1]);
    i2 = DOTW(wi, 2, W.bj[2]);
    dec0 = RCPF(1.f + __expf(-d0));
    dec1 = RCPF(1.f + __expf(-d1));
    dec2 = RCPF(1.f + __expf(-d2));
    float u = fmaf(bx, bx, fmaf(by, by, bz * bz));
    w = fmaf(u, fmaf(u, 2.6041667e-3f, -0.125f), 1.f);
    float s = fmaf(u, fmaf(u, 2.6041667e-4f, -2.0833333e-2f), 0.5f);
    qx = s * bz; qy = -s * by; qz = s * bx;
}

// build the step's 3x3 matrix (rows scaled by dec) + injection
__device__ __forceinline__ void step_matrix(const Wts& W, float4 q,
                                            float M[9], float& i0, float& i1, float& i2) {
    float dec0, dec1, dec2, w, qx, qy, qz;
    step_parts(W, q, dec0, dec1, dec2, w, qx, qy, qz, i0, i1, i2);
    float xx = qx*qx, yy = qy*qy, zz = qz*qz;
    float xy = qx*qy, xz = qx*qz, yz = qy*qz;
    float wxs = w*qx, wys = w*qy, wzs = w*qz;
    M[0] = dec0 * (1.f - 2.f*(yy+zz));
    M[1] = dec0 * (2.f*(xy - wzs));
    M[2] = dec0 * (2.f*(xz + wys));
    M[3] = dec1 * (2.f*(xy + wzs));
    M[4] = dec1 * (1.f - 2.f*(xx+zz));
    M[5] = dec1 * (2.f*(yz - wxs));
    M[6] = dec2 * (2.f*(xz - wys));
    M[7] = dec2 * (2.f*(yz + wxs));
    M[8] = dec2 * (1.f - 2.f*(xx+yy));
}

// A (12-vec affine) <- step0 map directly (peeled identity multiply)
__device__ __forceinline__ void step_init12(const Wts& W, float4 q, float A[12]) {
    float M[9], i0, i1, i2;
    step_matrix(W, q, M, i0, i1, i2);
#pragma unroll
    for (int e = 0; e < 9; ++e) A[e] = M[e];
    A[9] = i0; A[10] = i1; A[11] = i2;
}

// A <- step_map ∘ A
__device__ __forceinline__ void step_compose12(const Wts& W, float4 q, float A[12]) {
    float M[9], i0, i1, i2;
    step_matrix(W, q, M, i0, i1, i2);
    float n0 = fmaf(M[0], A[0], fmaf(M[1], A[3], M[2] * A[6]));
    float n1 = fmaf(M[0], A[1], fmaf(M[1], A[4], M[2] * A[7]));
    float n2 = fmaf(M[0], A[2], fmaf(M[1], A[5], M[2] * A[8]));
    float n3 = fmaf(M[3], A[0], fmaf(M[4], A[3], M[5] * A[6]));
    float n4 = fmaf(M[3], A[1], fmaf(M[4], A[4], M[5] * A[7]));
    float n5 = fmaf(M[3], A[2], fmaf(M[4], A[5], M[5] * A[8]));
    float n6 = fmaf(M[6], A[0], fmaf(M[7], A[3], M[8] * A[6]));
    float n7 = fmaf(M[6], A[1], fmaf(M[7], A[4], M[8] * A[7]));
    float n8 = fmaf(M[6], A[2], fmaf(M[7], A[5], M[8] * A[8]));
    float n9  = fmaf(M[0], A[9], fmaf(M[1], A[10], fmaf(M[2], A[11], i0)));
    float n10 = fmaf(M[3], A[9], fmaf(M[4], A[10], fmaf(M[5], A[11], i1)));
    float n11 = fmaf(M[6], A[9], fmaf(M[7], A[10], fmaf(M[8], A[11], i2)));
    A[0]=n0; A[1]=n1; A[2]=n2; A[3]=n3; A[4]=n4; A[5]=n5;
    A[6]=n6; A[7]=n7; A[8]=n8; A[9]=n9; A[10]=n10; A[11]=n11;
}

__device__ __forceinline__ void step_apply(const Wts& W, float4 q,
                                           float& vx, float& vy, float& vz) {
    float dec0, dec1, dec2, w, qx, qy, qz, i0, i1, i2;
    step_parts(W, q, dec0, dec1, dec2, w, qx, qy, qz, i0, i1, i2);
    float tx = 2.f * (qy * vz - qz * vy);
    float ty = 2.f * (qz * vx - qx * vz);
    float tz = 2.f * (qx * vy - qy * vx);
    float rx = vx + w * tx + (qy * tz - qz * ty);
    float ry = vy + w * ty + (qz * tx - qx * tz);
    float rz = vz + w * tz + (qx * ty - qy * tx);
    vx = fmaf(dec0, rx, i0);
    vy = fmaf(dec1, ry, i1);
    vz = fmaf(dec2, rz, i2);
}

// R = C ∘ P   (12-vec affine maps)
#define COMPOSE(R, C, P)                                                    \
    R[0] = fmaf(C[0], P[0], fmaf(C[1], P[3], C[2] * P[6]));                 \
    R[1] = fmaf(C[0], P[1], fmaf(C[1], P[4], C[2] * P[7]));                 \
    R[2] = fmaf(C[0], P[2], fmaf(C[1], P[5], C[2] * P[8]));                 \
    R[3] = fmaf(C[3], P[0], fmaf(C[4], P[3], C[5] * P[6]));                 \
    R[4] = fmaf(C[3], P[1], fmaf(C[4], P[4], C[5] * P[7]));                 \
    R[5] = fmaf(C[3], P[2], fmaf(C[4], P[5], C[5] * P[8]));                 \
    R[6] = fmaf(C[6], P[0], fmaf(C[7], P[3], C[8] * P[6]));                 \
    R[7] = fmaf(C[6], P[1], fmaf(C[7], P[4], C[8] * P[7]));                 \
    R[8] = fmaf(C[6], P[2], fmaf(C[7], P[5], C[8] * P[8]));                 \
    R[9]  = fmaf(C[0], P[9], fmaf(C[1], P[10], fmaf(C[2], P[11], C[9])));   \
    R[10] = fmaf(C[3], P[9], fmaf(C[4], P[10], fmaf(C[5], P[11], C[10])));  \
    R[11] = fmaf(C[6], P[9], fmaf(C[7], P[10], fmaf(C[8], P[11], C[11])));

__device__ __forceinline__ void pack12(const float A[12], float4* dst) {
    union { __half2 h2[8]; float4 f4[2]; } u;
#pragma unroll
    for (int e = 0; e < 6; ++e) u.h2[e] = __floats2half2_rn(A[2 * e], A[2 * e + 1]);
    u.h2[6] = __floats2half2_rn(0.f, 0.f);
    u.h2[7] = __floats2half2_rn(0.f, 0.f);
    dst[0] = u.f4[0];
    dst[1] = u.f4[1];
}

__device__ __forceinline__ void unpack12(const float4* src, float A[12]) {
    union { __half2 h2[8]; float4 f4[2]; } u;
    u.f4[0] = src[0]; u.f4[1] = src[1];
#pragma unroll
    for (int e = 0; e < 6; ++e) {
        float2 v = __half22float2(u.h2[e]);
        A[2 * e] = v.x; A[2 * e + 1] = v.y;
    }
}

// packed fp16 3-vector (8 B)
__device__ __forceinline__ uint2 packh3(float a, float b, float c) {
    __half2 lo = __floats2half2_rn(a, b);
    __half2 hi = __floats2half2_rn(c, 0.f);
    uint2 r;
    r.x = *(unsigned int*)&lo;
    r.y = *(unsigned int*)&hi;
    return r;
}

__device__ __forceinline__ void unpackh3(uint2 v, float& a, float& b, float& c) {
    __half2 lo = *(__half2*)&v.x;
    __half2 hi = *(__half2*)&v.y;
    float2 l2 = __half22float2(lo);
    float2 h2v = __half22float2(hi);
    a = l2.x; b = l2.y; c = h2v.x;
}

// ---------- kernel A (restructured): block = (n, b), threads = chunks ----------
// Weights are BLOCK-UNIFORM -> scalar loads + SGPR operands.
// AffH layout: [GG][CC] x 2 float4 (coalesced compose stores AND scan reads)
// AffLo layout: [CC][GG] x 2 float4 (scattered fire-and-forget stores; coalesced apply reads)
__global__ __launch_bounds__(256) void chunk_compose(
        const float* __restrict__ quat,
        const float4* __restrict__ Wc4,
        float4* __restrict__ AffH,
        float4* __restrict__ AffLo) {
    int n = blockIdx.x, b = blockIdx.y;
    int c = threadIdx.x;                 // chunk
    int g = b * 128 + n;

    Wts W;
    load_wts(Wc4, n, W);                 // uniform address -> s_load, W lives in SGPRs

    const float4* __restrict__ qp = (const float4*)(quat + (size_t)b * TT * 4) + c * LL;
    float4 q[LL];
#pragma unroll
    for (int t = 0; t < LL; ++t) q[t] = qp[t];

    // two independent half-chunk chains
    float Alo[12], Ahi[12];
    step_init12(W, q[0], Alo);
    step_init12(W, q[LL / 2], Ahi);
#pragma unroll
    for (int t = 1; t < LL / 2; ++t) {
        step_compose12(W, q[t], Alo);
        step_compose12(W, q[LL / 2 + t], Ahi);
    }
    pack12(Alo, AffLo + ((size_t)c * GG + g) * 2);      // scattered store, fire-and-forget
    float A[12];
    COMPOSE(A, Ahi, Alo);
    pack12(A, AffH + ((size_t)g * CC + c) * 2);         // coalesced store
}

// ---------- kernel B: wave-parallel scan, 4 chunks per lane (coalesced AffH reads) ----------
// Hs layout: [CC][GG] uint2 (fp16-packed chunk start state)
__global__ __launch_bounds__(256) void chunk_scan(
        const float4* __restrict__ AffH,
        uint2* __restrict__ Hs) {
    int g = (blockIdx.x * 256 + threadIdx.x) >> 6;   // chain (wave-uniform)
    int l = threadIdx.x & 63;                        // lane = quad index

    float m[4][12];
#pragma unroll
    for (int k = 0; k < 4; ++k)
        unpack12(AffH + ((size_t)g * CC + (4 * l + k)) * 2, m[k]);

    float q01[12], q012[12], Q[12];
    COMPOSE(q01, m[1], m[0]);
    COMPOSE(q012, m[2], q01);
    COMPOSE(Q, m[3], q012);

    float P[12];
#pragma unroll
    for (int k = 0; k < 12; ++k) P[k] = __shfl_up(Q[k], 1);
    if (l == 0) {
        P[0]=1.f; P[1]=0.f; P[2]=0.f; P[3]=0.f; P[4]=1.f; P[5]=0.f;
        P[6]=0.f; P[7]=0.f; P[8]=1.f; P[9]=0.f; P[10]=0.f; P[11]=0.f;
    }
#pragma unroll
    for (int sft = 1; sft < 64; sft <<= 1) {
        float S[12], N[12];
#pragma unroll
        for (int k = 0; k < 12; ++k) S[k] = __shfl_up(P[k], sft);
        COMPOSE(N, P, S);
        bool act = (l >= sft);
#pragma unroll
        for (int k = 0; k < 12; ++k) P[k] = act ? N[k] : P[k];
    }

    float h0 = P[9], h1 = P[10], h2 = P[11];
#pragma unroll
    for (int k = 0; k < 4; ++k) {
        Hs[(size_t)(4 * l + k) * GG + g] = packh3(h0, h1, h2);
        if (k < 3) {
            float n0 = fmaf(m[k][0], h0, fmaf(m[k][1], h1, fmaf(m[k][2], h2, m[k][9])));
            float n1 = fmaf(m[k][3], h0, fmaf(m[k][4], h1, fmaf(m[k][5], h2, m[k][10])));
            float n2 = fmaf(m[k][6], h0, fmaf(m[k][7], h1, fmaf(m[k][8], h2, m[k][11])));
            h0 = n0; h1 = n1; h2 = n2;
        }
    }
}

// ---------- kernel C: replay as TWO independent 4-step chains + projection ----------
__global__ __launch_bounds__(128) void chunk_apply_out(
        const float* __restrict__ quat,
        const float4* __restrict__ Wc4,
        const float* __restrict__ W_out,   // [DD][4]
        const uint2* __restrict__ Hs,      // [CC][GG] fp16-packed
        const float4* __restrict__ AffLo,  // [CC][GG] x 2 f4 (fp16 low-half map)
        float* __restrict__ out) {         // [BB][TT][4]
    int c = blockIdx.x, b = blockIdx.y, n = threadIdx.x;
    int g = b * 128 + n;

    const float4* __restrict__ qp = (const float4*)(quat + (size_t)b * TT * 4) + c * LL;
    float4 q[LL];
#pragma unroll
    for (int t = 0; t < LL; ++t) q[t] = qp[t];

    float ax, ay, az;
    unpackh3(Hs[(size_t)c * GG + g], ax, ay, az);
    float alo[12];
    unpack12(AffLo + ((size_t)c * GG + g) * 2, alo);

    Wts W;
    load_wts(Wc4, n, W);

    __shared__ float H[LL][HSTRIDE];

    int j0 = 3 * n;
    // chain A: h at chunk start; chain B: h after step LL/2-1 = Alo ∘ hA
    float bx = fmaf(alo[0], ax, fmaf(alo[1], ay, fmaf(alo[2], az, alo[9])));
    float by = fmaf(alo[3], ax, fmaf(alo[4], ay, fmaf(alo[5], az, alo[10])));
    float bz = fmaf(alo[6], ax, fmaf(alo[7], ay, fmaf(alo[8], az, alo[11])));

#pragma unroll
    for (int t = 0; t < LL / 2; ++t) {
        step_apply(W, q[t], ax, ay, az);
        step_apply(W, q[LL / 2 + t], bx, by, bz);
        H[t][j0] = ax; H[t][j0 + 1] = ay; H[t][j0 + 2] = az;
        H[LL / 2 + t][j0] = bx; H[LL / 2 + t][j0 + 1] = by; H[LL / 2 + t][j0 + 2] = bz;
    }
    __syncthreads();

    // projection: thread -> (row r = n>>4, part p = n&15); d = p + 16j
    int r = n >> 4, p = n & 15;
    float s0 = 0.f, s1 = 0.f, s2 = 0.f, s3 = 0.f;
#pragma unroll 8
    for (int j = 0; j < DD / 16; ++j) {
        int d = p + 16 * j;
        float hv = H[r][d];
        float4 wv = *(const float4*)(W_out + (size_t)d * 4);
        s0 = fmaf(hv, wv.x, s0);
        s1 = fmaf(hv, wv.y, s1);
        s2 = fmaf(hv, wv.z, s2);
        s3 = fmaf(hv, wv.w, s3);
    }
#pragma unroll
    for (int off = 1; off <= 8; off <<= 1) {
        s0 += __shfl_xor(s0, off);
        s1 += __shfl_xor(s1, off);
        s2 += __shfl_xor(s2, off);
        s3 += __shfl_xor(s3, off);
    }
    if (p == 0) {
        float norm = fmaxf(sqrtf(fmaf(s0, s0, fmaf(s1, s1, fmaf(s2, s2, s3 * s3)))), EPSF);
        float inv = RCPF(norm);
        float* outp = out + ((size_t)b * TT + (size_t)c * LL + r) * 4;
        *(float4*)outp = make_float4(s0 * inv, s1 * inv, s2 * inv, s3 * inv);
    }
}

extern "C" void kernel_launch(void* const* d_in, const int* in_sizes, int n_in,
                              void* d_out, int out_size, void* d_ws, size_t ws_size,
                              hipStream_t stream) {
    const float* quat  = (const float*)d_in[0];
    const float* W_in  = (const float*)d_in[1];
    const float* W_biv = (const float*)d_in[2];
    const float* b_biv = (const float*)d_in[3];
    const float* W_dec = (const float*)d_in[4];
    const float* b_dec = (const float*)d_in[5];
    const float* W_inj = (const float*)d_in[6];
    const float* b_inj = (const float*)d_in[7];
    const float* W_out = (const float*)d_in[8];
    float* out = (float*)d_out;

    const size_t AFF_OFF = 32768;                                  // Wc4: 30720 B
    const size_t AFF_B   = (size_t)CC * GG * 32;                   // 16.8 MB (fp16 packed)
    const size_t ALO_OFF = AFF_OFF + AFF_B;
    const size_t HS_OFF  = ALO_OFF + AFF_B;

    float*  Wc    = (float*)d_ws;
    float4* Wc4   = (float4*)d_ws;
    float4* AffH  = (float4*)((char*)d_ws + AFF_OFF);
    float4* AffLo = (float4*)((char*)d_ws + ALO_OFF);
    uint2*  Hs    = (uint2*)((char*)d_ws + HS_OFF);                // 4.2 MB

    precompute_wc<<<dim3(3, DD / 16), dim3(1024), 0, stream>>>(
        W_in, W_biv, W_dec, W_inj, b_biv, b_dec, b_inj, Wc);
    chunk_compose<<<dim3(128, BB), dim3(256), 0, stream>>>(quat, Wc4, AffH, AffLo);
    chunk_scan<<<dim3(GG / 4), dim3(256), 0, stream>>>(AffH, Hs);
    chunk_apply_out<<<dim3(CC, BB), dim3(128), 0, stream>>>(quat, Wc4, W_out, Hs, AffLo, out);
}